// Round 3
// baseline (104.919 us; speedup 1.0000x reference)
//
#include <hip/hip_runtime.h>
#include <hip/hip_bf16.h>
#include <stdint.h>

#define BATCH   512
#define INCH    20
#define FEAT    128
#define KACT    16
#define NUNIT   12

typedef short bf16x8 __attribute__((ext_vector_type(8)));
typedef float f32x4  __attribute__((ext_vector_type(4)));

#define BPACK_ELEMS (3*2*4*128*8)   // [ky][kk][g][f][j], k = kk*32+g*8+j -> (kx=k/20, c=k%20), 0 for k>=60
#define WHEAD_ELEMS (4*4*4*16*8)    // [agent][kt][g][action][j], f = kt*32+g*8+j

#define XIN_ELEMS   (34*34*20 + 64) // padded input [yy][xx][c] bf16 + slack (stays zero)
#define XLDS_STRIDE 136             // x tile [128 p][136] bf16

__device__ __forceinline__ uint16_t f2bf(float f) {
    union { float f; uint32_t u; } x{f};
    uint32_t u = x.u;
    return (uint16_t)((u + 0x7FFFu + ((u >> 16) & 1u)) >> 16);  // RNE
}

__device__ __forceinline__ uint32_t cvt_pk_bf16(float lo, float hi) {
    uint32_t r;
    asm("v_cvt_pk_bf16_f32 %0, %1, %2" : "=v"(r) : "v"(lo), "v"(hi));
    return r;
}

// ---- One-time weight repack (fp32 -> bf16 fragment order) ----
__global__ void repack_kernel(const float* __restrict__ conv_w,
                              const float* __restrict__ W_all,
                              uint16_t* __restrict__ Bpack,
                              uint16_t* __restrict__ Whead) {
    int idx = blockIdx.x * 256 + threadIdx.x;
    if (idx < BPACK_ELEMS) {
        int j = idx & 7, t = idx >> 3;
        int f = t & 127; t >>= 7;
        int g = t & 3;   t >>= 2;
        int kk = t & 1;  int ky = t >> 1;
        int k = kk * 32 + g * 8 + j;
        float v = 0.0f;
        if (k < 60) {
            int kx = k / 20, c = k % 20;
            v = conv_w[((f * INCH + c) * 3 + ky) * 3 + kx];
        }
        Bpack[idx] = f2bf(v);
    } else if (idx < BPACK_ELEMS + WHEAD_ELEMS) {
        int i = idx - BPACK_ELEMS;
        int j = i & 7, t = i >> 3;
        int a = t & 15; t >>= 4;
        int g = t & 3;  t >>= 2;
        int kt = t & 3; int ag = t >> 2;
        int f = kt * 32 + g * 8 + j;
        Whead[i] = f2bf(W_all[(ag * KACT + a) * FEAT + f]);
    }
}

// ---- Fused conv3x3 + relu/bias/mask + per-sample head GEMM, all MFMA ----
// 512 threads (8 waves); LDS ~81.2 KB -> 2 blocks/CU -> 4 waves/SIMD.
__global__ __launch_bounds__(512, 4) void fused_mfma_kernel(
    const float* __restrict__ states,    // [512,20,32,32]
    const int*   __restrict__ labels,    // [512]
    const float* __restrict__ maskings,  // [512,1,32,32]
    const float* __restrict__ conv_b,    // [128]
    const float* __restrict__ b_all,     // [4,16]
    const uint16_t* __restrict__ Bpack,
    const uint16_t* __restrict__ Whead,
    float*       __restrict__ out)       // [512*1024*12] ++ [512*1024*4]
{
    __shared__ __align__(16) uint16_t xin[XIN_ELEMS];           // 46,368 B
    __shared__ __align__(16) uint16_t xlds[128 * XLDS_STRIDE];  // 34,816 B

    const int b    = blockIdx.x;
    const int tid  = threadIdx.x;
    const int lane = tid & 63;
    const int w    = tid >> 6;     // 0..7
    const int l15  = lane & 15;
    const int g    = lane >> 4;    // 0..3
    const int mtq  = w >> 1;       // conv: wave owns mtiles {mtq*2, mtq*2+1}
    const int ntq  = w & 1;        // conv: wave owns features ntq*64 .. +63

    // ---- zero xin (incl. border + slack) ----
    for (int i = tid; i < (XIN_ELEMS * 2) / 16; i += 512)
        ((uint4*)xin)[i] = uint4{0, 0, 0, 0};
    __syncthreads();

    // ---- stage input: [c][y][x] fp32 -> xin[pos][c] bf16, b64 writes ----
    // item = cg*1024 + p : 4 channels (cg*4..+3) of position p per thread
    for (int t = 0; t < 10; ++t) {
        int i  = t * 512 + tid;
        int p  = i & 1023;
        int cg = i >> 10;           // 0..4
        int y  = p >> 5, x = p & 31;
        const float* sp = states + (size_t)b * (INCH * 1024) + cg * 4096 + p;
        float v0 = sp[0], v1 = sp[1024], v2 = sp[2048], v3 = sp[3072];
        uint64_t lo = cvt_pk_bf16(v0, v1);
        uint64_t hi = cvt_pk_bf16(v2, v3);
        *(uint64_t*)&xin[((y + 1) * 34 + (x + 1)) * 20 + cg * 4] = lo | (hi << 32);
    }

    // ---- per-lane invariants ----
    const int label = labels[b];
    float cb[4];
    #pragma unroll
    for (int nt = 0; nt < 4; ++nt) cb[nt] = conv_b[ntq * 64 + nt * 16 + l15];
    const float hbias = b_all[label * KACT + l15];

    bf16x8 Bh[4];
    #pragma unroll
    for (int kt = 0; kt < 4; ++kt)
        Bh[kt] = *(const bf16x8*)&Whead[(((label * 4 + kt) * 4 + g) * 16 + l15) * 8];

    __syncthreads();  // xin fully staged

    // ---- 8 chunks of 128 spatial positions (4 y-rows each) ----
    for (int chunk = 0; chunk < 8; ++chunk) {
        f32x4 acc[2][4];  // [mtl][nt]
        #pragma unroll
        for (int i = 0; i < 2; ++i)
            #pragma unroll
            for (int j = 0; j < 4; ++j)
                acc[i][j] = f32x4{0.f, 0.f, 0.f, 0.f};

        // conv: K-slice outer (keeps Bc live-range at 16 VGPRs)
        #pragma unroll
        for (int ky = 0; ky < 3; ++ky)
            #pragma unroll
            for (int kk = 0; kk < 2; ++kk) {
                bf16x8 Bcf[4];
                #pragma unroll
                for (int nt = 0; nt < 4; ++nt) {
                    int f = ntq * 64 + nt * 16 + l15;
                    Bcf[nt] = *(const bf16x8*)&Bpack[((((ky * 2 + kk) * 4 + g) * 128 + f) * 8)];
                }
                #pragma unroll
                for (int mtl = 0; mtl < 2; ++mtl) {
                    const int mt = mtq * 2 + mtl;
                    const int y  = chunk * 4 + (mt >> 1);
                    const int x0 = (mt & 1) * 16;
                    const int pos = (y + ky) * 34 + x0 + l15;
                    const uint64_t* ap = (const uint64_t*)&xin[pos * 20 + g * 8];
                    union { uint64_t u[2]; bf16x8 v; } A;
                    A.u[0] = ap[kk * 8 + 0];
                    A.u[1] = ap[kk * 8 + 1];
                    #pragma unroll
                    for (int nt = 0; nt < 4; ++nt)
                        acc[mtl][nt] = __builtin_amdgcn_mfma_f32_16x16x32_bf16(
                            A.v, Bcf[nt], acc[mtl][nt], 0, 0, 0);
                }
            }

        __syncthreads();  // head(chunk-1) done reading xlds

        // epilogue: bias+relu+mask, cvt_pk to bf16 pairs, b32 writes into xlds[p][f]
        #pragma unroll
        for (int mtl = 0; mtl < 2; ++mtl) {
            const int mt    = mtq * 2 + mtl;
            const int pbase = mt * 16 + g * 4;
            const float4 m4 = *(const float4*)&maskings[(size_t)b * 1024 + chunk * 128 + pbase];
            const float mm[4] = {m4.x, m4.y, m4.z, m4.w};
            #pragma unroll
            for (int nt = 0; nt < 4; ++nt) {
                const int f  = ntq * 64 + nt * 16 + l15;
                const int fp = f & ~1;
                float xv[4];
                #pragma unroll
                for (int j = 0; j < 4; ++j)
                    xv[j] = fmaxf(acc[mtl][nt][j] + cb[nt], 0.f) * mm[j];
                float xo[4];
                #pragma unroll
                for (int j = 0; j < 4; ++j) xo[j] = __shfl_xor(xv[j], 1, 64);
                uint32_t w0, w1; int r0, r1;
                if (!(l15 & 1)) {   // even feature lane: rows 0,1 of the quad
                    w0 = cvt_pk_bf16(xv[0], xo[0]); r0 = 0;
                    w1 = cvt_pk_bf16(xv[1], xo[1]); r1 = 1;
                } else {            // odd feature lane: rows 2,3
                    w0 = cvt_pk_bf16(xo[2], xv[2]); r0 = 2;
                    w1 = cvt_pk_bf16(xo[3], xv[3]); r1 = 3;
                }
                *(uint32_t*)&xlds[(pbase + r0) * XLDS_STRIDE + fp] = w0;
                *(uint32_t*)&xlds[(pbase + r1) * XLDS_STRIDE + fp] = w1;
            }
        }

        __syncthreads();  // xlds ready

        // head GEMM: wave w <-> mtile w; K=128 = 4 kt slices
        {
            f32x4 hacc = f32x4{0.f, 0.f, 0.f, 0.f};
            #pragma unroll
            for (int kt = 0; kt < 4; ++kt) {
                const bf16x8* ax = (const bf16x8*)&xlds[(w * 16 + l15) * XLDS_STRIDE + kt * 32 + g * 8];
                hacc = __builtin_amdgcn_mfma_f32_16x16x32_bf16(*ax, Bh[kt], hacc, 0, 0, 0);
            }
            const size_t prow = (size_t)b * 1024 + chunk * 128 + w * 16 + g * 4;
            #pragma unroll
            for (int j = 0; j < 4; ++j) {
                const float v = hacc[j] + hbias;
                const size_t pos = prow + j;
                if (l15 < NUNIT) out[pos * NUNIT + l15] = v;
                else             out[(size_t)BATCH * 1024 * NUNIT + pos * (KACT - NUNIT) + (l15 - NUNIT)] = v;
            }
        }
    }
}

extern "C" void kernel_launch(void* const* d_in, const int* in_sizes, int n_in,
                              void* d_out, int out_size, void* d_ws, size_t ws_size,
                              hipStream_t stream) {
    const float* states   = (const float*)d_in[0];
    const int*   labels   = (const int*)d_in[1];
    const float* maskings = (const float*)d_in[2];
    const float* conv_w   = (const float*)d_in[3];
    const float* conv_b   = (const float*)d_in[4];
    const float* W_all    = (const float*)d_in[5];
    const float* b_all    = (const float*)d_in[6];
    float* out = (float*)d_out;

    uint16_t* Bpack = (uint16_t*)d_ws;
    uint16_t* Whead = Bpack + BPACK_ELEMS;

    repack_kernel<<<(BPACK_ELEMS + WHEAD_ELEMS + 255) / 256, 256, 0, stream>>>(
        conv_w, W_all, Bpack, Whead);
    fused_mfma_kernel<<<BATCH, 512, 0, stream>>>(
        states, labels, maskings, conv_b, b_all, Bpack, Whead, out);
}

// Round 4
// 91.073 us; speedup vs baseline: 1.1520x; 1.1520x over previous
//
#include <hip/hip_runtime.h>
#include <hip/hip_bf16.h>
#include <stdint.h>

#define BATCH   512
#define INCH    20
#define FEAT    128
#define KACT    16
#define NUNIT   12

typedef short bf16x8 __attribute__((ext_vector_type(8)));
typedef float f32x4  __attribute__((ext_vector_type(4)));

#define BPACK_ELEMS (3*2*4*128*8)   // [ky][kk][g][f][j], k = kk*32+g*8+j -> (kx=k/20, c=k%20), 0 for k>=60
#define WHEAD_ELEMS (4*4*4*16*8)    // [agent][kt][g][action][j], f = kt*32+g*8+j

#define XIN_SLOT    680             // 34 pos * 20 ch (bf16 elems) per row-slot
#define XIN_ELEMS   (8*XIN_SLOT + 64)  // 8-slot rolling buffer + OOB slack (stays zero)
#define XLDS_STRIDE 136             // x tile [64 pos][136] bf16

__device__ __forceinline__ uint16_t f2bf(float f) {
    union { float f; uint32_t u; } x{f};
    uint32_t u = x.u;
    return (uint16_t)((u + 0x7FFFu + ((u >> 16) & 1u)) >> 16);  // RNE
}

__device__ __forceinline__ uint32_t cvt_pk_bf16(float lo, float hi) {
    uint32_t r;
    asm("v_cvt_pk_bf16_f32 %0, %1, %2" : "=v"(r) : "v"(lo), "v"(hi));
    return r;
}

// ---- One-time weight repack (fp32 -> bf16 fragment order) ----
__global__ void repack_kernel(const float* __restrict__ conv_w,
                              const float* __restrict__ W_all,
                              uint16_t* __restrict__ Bpack,
                              uint16_t* __restrict__ Whead) {
    int idx = blockIdx.x * 256 + threadIdx.x;
    if (idx < BPACK_ELEMS) {
        int j = idx & 7, t = idx >> 3;
        int f = t & 127; t >>= 7;
        int g = t & 3;   t >>= 2;
        int kk = t & 1;  int ky = t >> 1;
        int k = kk * 32 + g * 8 + j;
        float v = 0.0f;
        if (k < 60) {
            int kx = k / 20, c = k % 20;
            v = conv_w[((f * INCH + c) * 3 + ky) * 3 + kx];
        }
        Bpack[idx] = f2bf(v);
    } else if (idx < BPACK_ELEMS + WHEAD_ELEMS) {
        int i = idx - BPACK_ELEMS;
        int j = i & 7, t = i >> 3;
        int a = t & 15; t >>= 4;
        int g = t & 3;  t >>= 2;
        int kt = t & 3; int ag = t >> 2;
        int f = kt * 32 + g * 8 + j;
        Whead[i] = f2bf(W_all[(ag * KACT + a) * FEAT + f]);
    }
}

// Stage padded rows rA, rA+1 into the rolling buffer (immediate form, init only).
__device__ __forceinline__ void stage_pair_now(uint16_t* xin, const float* states,
                                               int b, int y0, int rA, int tid) {
    #pragma unroll
    for (int t = 0; t < 2; ++t) {
        int item = t * 256 + tid;
        bool active = (t == 0) || (tid < 64);
        if (active) {
            int ri = (item >= 160) ? 1 : 0;
            int r  = rA + ri;
            int li = item - ri * 160;
            int cg = li >> 5, p = li & 31;
            if (r <= y0 + 17 && r <= 33) {
                int y = r - 1;
                float v0 = 0.f, v1 = 0.f, v2 = 0.f, v3 = 0.f;
                if (y >= 0 && y <= 31) {
                    const float* sp = states + (size_t)b * (INCH * 1024) + cg * 4096 + y * 32 + p;
                    v0 = sp[0]; v1 = sp[1024]; v2 = sp[2048]; v3 = sp[3072];
                }
                uint64_t lo = cvt_pk_bf16(v0, v1);
                uint64_t hi = cvt_pk_bf16(v2, v3);
                *(uint64_t*)&xin[(r & 7) * XIN_SLOT + (p + 1) * 20 + cg * 4] = lo | (hi << 32);
            }
        }
    }
}

// ---- Fused conv3x3 + relu/bias/mask + per-sample head GEMM, all MFMA ----
// 1024 blocks (2 per sample, 16 output rows each); 256 threads; LDS ~28.4 KB.
__global__ __launch_bounds__(256, 3) void fused_mfma_kernel(
    const float* __restrict__ states,    // [512,20,32,32]
    const int*   __restrict__ labels,    // [512]
    const float* __restrict__ maskings,  // [512,1,32,32]
    const float* __restrict__ conv_b,    // [128]
    const float* __restrict__ b_all,     // [4,16]
    const uint16_t* __restrict__ Bpack,
    const uint16_t* __restrict__ Whead,
    float*       __restrict__ out)       // [512*1024*12] ++ [512*1024*4]
{
    __shared__ __align__(16) uint16_t xin[XIN_ELEMS];              // 11,008 B
    __shared__ __align__(16) uint16_t xlds[64 * XLDS_STRIDE];      // 17,408 B

    const int b    = blockIdx.x >> 1;
    const int y0   = (blockIdx.x & 1) << 4;   // output rows y0..y0+15
    const int tid  = threadIdx.x;
    const int lane = tid & 63;
    const int w    = tid >> 6;     // 0..3
    const int l15  = lane & 15;
    const int g    = lane >> 4;    // 0..3
    const int mtq  = w >> 1;       // conv: wave owns mtiles {mtq*2, mtq*2+1} of 4
    const int ntq  = w & 1;        // conv: wave owns features ntq*64 .. +63

    // ---- zero xin (slots + slack) ----
    for (int i = tid; i < XIN_ELEMS / 8; i += 256)
        ((uint4*)xin)[i] = uint4{0, 0, 0, 0};
    __syncthreads();

    // ---- init: stage padded rows y0 .. y0+3 ----
    stage_pair_now(xin, states, b, y0, y0,     tid);
    stage_pair_now(xin, states, b, y0, y0 + 2, tid);

    // ---- per-lane invariants ----
    const int label = labels[b];
    float cb[4];
    #pragma unroll
    for (int nt = 0; nt < 4; ++nt) cb[nt] = conv_b[ntq * 64 + nt * 16 + l15];
    const float hbias = b_all[label * KACT + l15];

    bf16x8 Bh[4];
    #pragma unroll
    for (int kt = 0; kt < 4; ++kt)
        Bh[kt] = *(const bf16x8*)&Whead[(((label * 4 + kt) * 4 + g) * 16 + l15) * 8];

    __syncthreads();  // init rows staged

    // ---- 8 chunks of 64 positions (2 y-rows each) ----
    for (int chunk = 0; chunk < 8; ++chunk) {
        const int Y = y0 + chunk * 2;

        // --- (1) issue prefetch loads for padded rows Y+4, Y+5 (write later) ---
        float pv0[4] = {0.f, 0.f, 0.f, 0.f};
        float pv1[4] = {0.f, 0.f, 0.f, 0.f};
        bool  wr0 = false, wr1 = false;
        int   wa0 = 0, wa1 = 0;
        {
            const int rP = Y + 4;
            // item0 = tid
            {
                int ri = (tid >= 160) ? 1 : 0;
                int r  = rP + ri;
                int li = tid - ri * 160;
                int cg = li >> 5, p = li & 31;
                if (r <= y0 + 17 && r <= 33) {
                    wr0 = true;
                    wa0 = (r & 7) * XIN_SLOT + (p + 1) * 20 + cg * 4;
                    int y = r - 1;
                    if (y <= 31) {
                        const float* sp = states + (size_t)b * (INCH * 1024) + cg * 4096 + y * 32 + p;
                        pv0[0] = sp[0]; pv0[1] = sp[1024]; pv0[2] = sp[2048]; pv0[3] = sp[3072];
                    }
                }
            }
            // item1 = 256 + tid (tid < 64)
            if (tid < 64) {
                int item = 256 + tid;   // >= 160 -> second row
                int r  = rP + 1;
                int li = item - 160;
                int cg = li >> 5, p = li & 31;
                if (r <= y0 + 17 && r <= 33) {
                    wr1 = true;
                    wa1 = (r & 7) * XIN_SLOT + (p + 1) * 20 + cg * 4;
                    int y = r - 1;
                    if (y <= 31) {
                        const float* sp = states + (size_t)b * (INCH * 1024) + cg * 4096 + y * 32 + p;
                        pv1[0] = sp[0]; pv1[1] = sp[1024]; pv1[2] = sp[2048]; pv1[3] = sp[3072];
                    }
                }
            }
        }

        // --- (2) conv MFMAs ---
        f32x4 acc[2][4];
        #pragma unroll
        for (int i = 0; i < 2; ++i)
            #pragma unroll
            for (int j = 0; j < 4; ++j)
                acc[i][j] = f32x4{0.f, 0.f, 0.f, 0.f};

        #pragma unroll
        for (int ky = 0; ky < 3; ++ky)
            #pragma unroll
            for (int kk = 0; kk < 2; ++kk) {
                bf16x8 Bcf[4];
                #pragma unroll
                for (int nt = 0; nt < 4; ++nt) {
                    int f = ntq * 64 + nt * 16 + l15;
                    Bcf[nt] = *(const bf16x8*)&Bpack[((((ky * 2 + kk) * 4 + g) * 128 + f) * 8)];
                }
                #pragma unroll
                for (int mtl = 0; mtl < 2; ++mtl) {
                    const int mt = mtq * 2 + mtl;
                    const int r  = Y + (mt >> 1) + ky;        // absolute padded row
                    const int x0 = (mt & 1) * 16;
                    const uint64_t* ap = (const uint64_t*)&xin[(r & 7) * XIN_SLOT + (x0 + l15) * 20 + g * 8];
                    union { uint64_t u[2]; bf16x8 v; } A;
                    A.u[0] = ap[kk * 8 + 0];
                    A.u[1] = ap[kk * 8 + 1];
                    #pragma unroll
                    for (int nt = 0; nt < 4; ++nt)
                        acc[mtl][nt] = __builtin_amdgcn_mfma_f32_16x16x32_bf16(
                            A.v, Bcf[nt], acc[mtl][nt], 0, 0, 0);
                }
            }

        // --- (3) finish staging (write prefetched rows; read next chunk) ---
        if (wr0) {
            uint64_t lo = cvt_pk_bf16(pv0[0], pv0[1]);
            uint64_t hi = cvt_pk_bf16(pv0[2], pv0[3]);
            *(uint64_t*)&xin[wa0] = lo | (hi << 32);
        }
        if (wr1) {
            uint64_t lo = cvt_pk_bf16(pv1[0], pv1[1]);
            uint64_t hi = cvt_pk_bf16(pv1[2], pv1[3]);
            *(uint64_t*)&xin[wa1] = lo | (hi << 32);
        }

        __syncthreads();  // [alpha] head(chunk-1) done reading xlds

        // --- (4) epilogue: bias+relu+mask, pack bf16, write xlds[p][f] ---
        #pragma unroll
        for (int mtl = 0; mtl < 2; ++mtl) {
            const int mt    = mtq * 2 + mtl;
            const int pbase = mt * 16 + g * 4;   // position within chunk (xlds row)
            const int gx    = (mt & 1) * 16 + g * 4;
            const float4 m4 = *(const float4*)&maskings[(size_t)b * 1024 + (Y + (mt >> 1)) * 32 + gx];
            const float mm[4] = {m4.x, m4.y, m4.z, m4.w};
            #pragma unroll
            for (int nt = 0; nt < 4; ++nt) {
                const int f  = ntq * 64 + nt * 16 + l15;
                const int fp = f & ~1;
                float xv[4];
                #pragma unroll
                for (int j = 0; j < 4; ++j)
                    xv[j] = fmaxf(acc[mtl][nt][j] + cb[nt], 0.f) * mm[j];
                float xo[4];
                #pragma unroll
                for (int j = 0; j < 4; ++j) xo[j] = __shfl_xor(xv[j], 1, 64);
                uint32_t w0, w1; int r0, r1;
                if (!(l15 & 1)) {   // even feature lane: rows 0,1 of the quad
                    w0 = cvt_pk_bf16(xv[0], xo[0]); r0 = 0;
                    w1 = cvt_pk_bf16(xv[1], xo[1]); r1 = 1;
                } else {            // odd feature lane: rows 2,3
                    w0 = cvt_pk_bf16(xo[2], xv[2]); r0 = 2;
                    w1 = cvt_pk_bf16(xo[3], xv[3]); r1 = 3;
                }
                *(uint32_t*)&xlds[(pbase + r0) * XLDS_STRIDE + fp] = w0;
                *(uint32_t*)&xlds[(pbase + r1) * XLDS_STRIDE + fp] = w1;
            }
        }

        __syncthreads();  // [beta] xlds ready

        // --- (5) head GEMM: wave w <-> mtile w; K=128 = 4 kt slices ---
        {
            f32x4 hacc = f32x4{0.f, 0.f, 0.f, 0.f};
            #pragma unroll
            for (int kt = 0; kt < 4; ++kt) {
                const bf16x8* ax = (const bf16x8*)&xlds[(w * 16 + l15) * XLDS_STRIDE + kt * 32 + g * 8];
                hacc = __builtin_amdgcn_mfma_f32_16x16x32_bf16(*ax, Bh[kt], hacc, 0, 0, 0);
            }
            const int gx = (w & 1) * 16 + g * 4;
            const size_t prow = (size_t)b * 1024 + (Y + (w >> 1)) * 32 + gx;
            #pragma unroll
            for (int j = 0; j < 4; ++j) {
                const float v = hacc[j] + hbias;
                const size_t pos = prow + j;
                if (l15 < NUNIT) out[pos * NUNIT + l15] = v;
                else             out[(size_t)BATCH * 1024 * NUNIT + pos * (KACT - NUNIT) + (l15 - NUNIT)] = v;
            }
        }
    }
}

extern "C" void kernel_launch(void* const* d_in, const int* in_sizes, int n_in,
                              void* d_out, int out_size, void* d_ws, size_t ws_size,
                              hipStream_t stream) {
    const float* states   = (const float*)d_in[0];
    const int*   labels   = (const int*)d_in[1];
    const float* maskings = (const float*)d_in[2];
    const float* conv_w   = (const float*)d_in[3];
    const float* conv_b   = (const float*)d_in[4];
    const float* W_all    = (const float*)d_in[5];
    const float* b_all    = (const float*)d_in[6];
    float* out = (float*)d_out;

    uint16_t* Bpack = (uint16_t*)d_ws;
    uint16_t* Whead = Bpack + BPACK_ELEMS;

    repack_kernel<<<(BPACK_ELEMS + WHEAD_ELEMS + 255) / 256, 256, 0, stream>>>(
        conv_w, W_all, Bpack, Whead);
    fused_mfma_kernel<<<BATCH * 2, 256, 0, stream>>>(
        states, labels, maskings, conv_b, b_all, Bpack, Whead, out);
}